// Round 4
// baseline (8337.354 us; speedup 1.0000x reference)
//
#include <hip/hip_runtime.h>
#include <stdint.h>

// GRU S=512, B=64, D=H=1024, L=2 — persistent 2-stage K-fused pipeline.
// 128 WGs = 2 tasks x 64 slices (16 hidden units each), 1 WG/CU:
//   task0 (L0): [h0(t-1); x_t]    (K=2048) @ [Whh0; Wih0] -> gates -> h0(t), o0r
//   task1 (L1): [h1(t-1); out0(t)](K=2048) @ [Whh1; Wih1] -> gates -> h1(t), d_out
// Waves are K-partitioned (wave w owns kchunks 16w..16w+15): waves 0,1 = h-part
// (sc1 loads, device-coherent), waves 2,3 = x/o0r part. Each B-fragment is read
// by exactly ONE wave -> B streams global->register (no LDS in K-loop). Partial
// accumulators (r,z sum over all waves; n kept split h-part/x-part for the
// r*(h_n) GRU form) reduced via one LDS exchange per step; wave 0 does the
// nonlinearity, h-state lives in wave-0 registers.
// Sync: per-slice monotonic flag stores (sc1, no RMW) + 64-lane ballot polls.

#define SLEN 512
#define HB   65536   // elems of one (64,1024) slab

typedef __attribute__((ext_vector_type(8))) short bf16x8;
typedef __attribute__((ext_vector_type(4))) float f32x4;
typedef __attribute__((ext_vector_type(8))) uint16_t u16x8;

struct Chunk { bf16x8 a[4]; bf16x8 b[3]; };

__device__ __forceinline__ uint16_t f32_to_bf16(float f) {
  uint32_t u = __float_as_uint(f);
  uint32_t r = u + 0x7FFFu + ((u >> 16) & 1u);
  return (uint16_t)(r >> 16);
}
__device__ __forceinline__ float sigmoid_fast(float x) { return 1.0f / (1.0f + __expf(-x)); }
__device__ __forceinline__ float tanh_fast(float x) { return 1.0f - 2.0f / (1.0f + __expf(2.0f * x)); }
__device__ __forceinline__ void drain_vmem() {
  asm volatile("s_waitcnt vmcnt(0)" ::: "memory");
}
__device__ __forceinline__ void st_u16_llc(uint16_t* p, uint16_t v) {
  __hip_atomic_store(p, v, __ATOMIC_RELAXED, __HIP_MEMORY_SCOPE_AGENT);
}

// ---- K-loop load machinery --------------------------------------------------
// One chunk = one kchunk (K=32): 4 A-frags (one per M-tile, 16B/lane) +
// 3 B-frags (r,z,n gates, 16B/lane). ALL K-loop vmem lives in these asm
// batches so the hand-counted vmcnt(N) waits are exact.

__device__ __forceinline__ void issue7_sc1(const uint16_t* a0, const uint16_t* a1,
                                           const uint16_t* a2, const uint16_t* a3,
                                           const uint16_t* bp, Chunk& c) {
  asm volatile(
      "global_load_dwordx4 %0, %7, off sc1\n\t"
      "global_load_dwordx4 %1, %8, off sc1\n\t"
      "global_load_dwordx4 %2, %9, off sc1\n\t"
      "global_load_dwordx4 %3, %10, off sc1\n\t"
      "global_load_dwordx4 %4, %11, off\n\t"
      "global_load_dwordx4 %5, %11, off offset:1024\n\t"
      "global_load_dwordx4 %6, %11, off offset:2048"
      : "=&v"(c.a[0]), "=&v"(c.a[1]), "=&v"(c.a[2]), "=&v"(c.a[3]),
        "=&v"(c.b[0]), "=&v"(c.b[1]), "=&v"(c.b[2])
      : "v"(a0), "v"(a1), "v"(a2), "v"(a3), "v"(bp)
      : "memory");
}
__device__ __forceinline__ void issue7_plain(const uint16_t* a0, const uint16_t* a1,
                                             const uint16_t* a2, const uint16_t* a3,
                                             const uint16_t* bp, Chunk& c) {
  asm volatile(
      "global_load_dwordx4 %0, %7, off\n\t"
      "global_load_dwordx4 %1, %8, off\n\t"
      "global_load_dwordx4 %2, %9, off\n\t"
      "global_load_dwordx4 %3, %10, off\n\t"
      "global_load_dwordx4 %4, %11, off\n\t"
      "global_load_dwordx4 %5, %11, off offset:1024\n\t"
      "global_load_dwordx4 %6, %11, off offset:2048"
      : "=&v"(c.a[0]), "=&v"(c.a[1]), "=&v"(c.a[2]), "=&v"(c.a[3]),
        "=&v"(c.b[0]), "=&v"(c.b[1]), "=&v"(c.b[2])
      : "v"(a0), "v"(a1), "v"(a2), "v"(a3), "v"(bp)
      : "memory");
}

#define MK_WAIT(NAME, NSTR)                                                     \
  __device__ __forceinline__ void NAME(Chunk& c) {                              \
    asm volatile("s_waitcnt vmcnt(" NSTR ")"                                    \
                 : "+v"(c.a[0]), "+v"(c.a[1]), "+v"(c.a[2]), "+v"(c.a[3]),      \
                   "+v"(c.b[0]), "+v"(c.b[1]), "+v"(c.b[2])::"memory");         \
  }
MK_WAIT(wait21, "21")
MK_WAIT(wait14, "14")
MK_WAIT(wait7, "7")
MK_WAIT(wait0, "0")

// ---- prep kernels -----------------------------------------------------------

__global__ __launch_bounds__(256) void convert_x(const float* __restrict__ src,
                                                 uint16_t* __restrict__ dst) {
  size_t i = ((size_t)blockIdx.x * 256 + threadIdx.x) * 8;
  const float4* s = (const float4*)(src + i);
  float4 a = s[0], b = s[1];
  u16x8 v;
  v[0] = f32_to_bf16(a.x); v[1] = f32_to_bf16(a.y);
  v[2] = f32_to_bf16(a.z); v[3] = f32_to_bf16(a.w);
  v[4] = f32_to_bf16(b.x); v[5] = f32_to_bf16(b.y);
  v[6] = f32_to_bf16(b.z); v[7] = f32_to_bf16(b.w);
  *(u16x8*)(dst + i) = v;
}

// Pack [Whh ; Wih] (each 3072x1024 f32 row-major) into per-(slice,wave) MFMA
// B-fragment streams over fused K=2048 (k<1024 -> Whh, k>=1024 -> Wih):
// dst[(s*4+w)*24576 + ((kc*3 + n)*64 + lane)*8 .. +7], fragment =
// W[n*1024 + s*16 + (lane&15)][(w*16+kc)*32 + (lane>>4)*8 ..+7]
__global__ __launch_bounds__(256) void pack_cat(const float* __restrict__ whh,
                                                const float* __restrict__ wih,
                                                uint16_t* __restrict__ dst) {
  int tid = blockIdx.x * 256 + threadIdx.x;   // < 786432
  int lane = tid & 63;
  int c1 = tid >> 6;
  int n = c1 % 3;
  int c2 = c1 / 3;
  int kc = c2 & 15;
  int c3 = c2 >> 4;
  int w = c3 & 3;
  int s = c3 >> 2;
  int row = n * 1024 + s * 16 + (lane & 15);
  int kg = (w * 16 + kc) * 32 + (lane >> 4) * 8;
  const float* src = (kg < 1024) ? (whh + (size_t)row * 1024 + kg)
                                 : (wih + (size_t)row * 1024 + (kg - 1024));
  u16x8 v;
#pragma unroll
  for (int j = 0; j < 8; ++j) v[j] = f32_to_bf16(src[j]);
  size_t off = (size_t)(s * 4 + w) * 24576 + ((size_t)(kc * 3 + n) * 64 + lane) * 8;
  *(u16x8*)(dst + off) = v;
}

__global__ __launch_bounds__(256) void init_state(const float* __restrict__ hx,
                                                  uint16_t* __restrict__ h0b,
                                                  uint16_t* __restrict__ h1b,
                                                  int* __restrict__ flags) {
  int i = blockIdx.x * 256 + threadIdx.x;   // 65536
  h0b[HB + i] = f32_to_bf16(hx[i]);         // slot 1 holds h(-1)
  h1b[HB + i] = f32_to_bf16(hx[HB + i]);
  if (blockIdx.x == 0) flags[threadIdx.x] = 0;
}

// ---- persistent kernel ------------------------------------------------------

__global__ __launch_bounds__(256, 1) void gru_persist(
    const uint16_t* __restrict__ x_bf,
    const uint16_t* __restrict__ w0cat, const uint16_t* __restrict__ w1cat,
    const float* __restrict__ bih0, const float* __restrict__ bhh0,
    const float* __restrict__ bih1, const float* __restrict__ bhh1,
    const float* __restrict__ hx,
    uint16_t* __restrict__ o0r,
    uint16_t* __restrict__ h0b, uint16_t* __restrict__ h1b,
    int* __restrict__ flags,
    float* __restrict__ out) {
  __shared__ __align__(16) char red[3 * 64 * 208];   // 39936 B reduction buffer

  const int task = blockIdx.x >> 6;         // 0 = layer0, 1 = layer1
  const int s = blockIdx.x & 63;
  const int tid = threadIdx.x;
  const int lane = tid & 63;
  const int wv = tid >> 6;
  const int r15 = lane & 15;
  const int q = lane >> 4;
  const int c = s * 16 + r15;               // hidden-unit column

  int* F1 = flags;                          // task0 per-slice progress
  int* F3 = flags + 64;                     // task1 per-slice progress

  const uint16_t* wb = (task ? w1cat : w0cat) + (size_t)(s * 4 + wv) * 24576;
  const float* bih = task ? bih1 : bih0;
  const float* bhh = task ? bhh1 : bhh0;
  const uint16_t* hb = task ? h1b : h0b;
  uint16_t* hwr = task ? h1b : h0b;
  int* myF = task ? F3 : F1;

  float hreg[4][4];
  float bR = 0.f, bZ = 0.f, bihN = 0.f, bhhN = 0.f;
  if (wv == 0) {
    bR = bih[c] + bhh[c];
    bZ = bih[1024 + c] + bhh[1024 + c];
    bihN = bih[2048 + c];
    bhhN = bhh[2048 + c];
#pragma unroll
    for (int m = 0; m < 4; ++m)
#pragma unroll
      for (int rg = 0; rg < 4; ++rg)
        hreg[m][rg] = hx[(size_t)task * HB + (size_t)(m * 16 + q * 4 + rg) * 1024 + c];
  }

  for (int t = 0; t < SLEN; ++t) {
    // ---- poll (wave 0 only): ballot over 64 per-slice flags ----
    if (wv == 0) {
      const int need1 = task ? (t + 1) : t;       // o0r[t] ready / self h0
      const int need3 = task ? t : (t - 7);       // self h1 / o0r ring free
      int guard = 0;
      for (;;) {
        int v1 = __hip_atomic_load(F1 + lane, __ATOMIC_RELAXED, __HIP_MEMORY_SCOPE_AGENT);
        int v3 = __hip_atomic_load(F3 + lane, __ATOMIC_RELAXED, __HIP_MEMORY_SCOPE_AGENT);
        bool ok = (v1 >= need1) && (v3 >= need3);
        if (__ballot(ok) == ~0ULL) break;
        if (guard < 8) __builtin_amdgcn_s_sleep(1);
        else if (guard < 32) __builtin_amdgcn_s_sleep(4);
        else __builtin_amdgcn_s_sleep(16);
        if (++guard > (1 << 20)) break;           // safety valve
      }
    }
    __syncthreads();

    // ---- K-loop: wave wv owns global kchunks [wv*16, wv*16+16) ----
    f32x4 acc[3][4];
#pragma unroll
    for (int n = 0; n < 3; ++n)
#pragma unroll
      for (int m = 0; m < 4; ++m) acc[n][m] = (f32x4){0.f, 0.f, 0.f, 0.f};

    const uint16_t* ap0;
    bool sc1a;
    int koff;
    if (wv < 2) {                                  // h-part (k 0..1023)
      ap0 = hb + (size_t)((t + 1) & 1) * HB;       // slot holding h(t-1)
      sc1a = true;
      koff = wv * 512;
    } else if (task == 0) {                        // x-part, layer 0
      ap0 = x_bf + (size_t)t * HB;
      sc1a = false;
      koff = (wv - 2) * 512;
    } else {                                       // out0-part, layer 1
      ap0 = o0r + (size_t)(t & 7) * HB;
      sc1a = true;
      koff = (wv - 2) * 512;
    }
    const uint16_t* a0 = ap0 + (size_t)r15 * 1024 + koff + q * 8;
    const uint16_t* a1 = a0 + 16 * 1024;
    const uint16_t* a2 = a0 + 32 * 1024;
    const uint16_t* a3 = a0 + 48 * 1024;
    const uint16_t* bp = wb + lane * 8;

    Chunk pipe[4];
#pragma unroll
    for (int p = 0; p < 4; ++p) {
      if (sc1a) issue7_sc1(a0, a1, a2, a3, bp, pipe[p]);
      else      issue7_plain(a0, a1, a2, a3, bp, pipe[p]);
      a0 += 32; a1 += 32; a2 += 32; a3 += 32; bp += 1536;
    }
#pragma unroll
    for (int kc = 0; kc < 16; ++kc) {
      Chunk& cur = pipe[kc & 3];
      if (kc <= 12) wait21(cur);
      else if (kc == 13) wait14(cur);
      else if (kc == 14) wait7(cur);
      else wait0(cur);
#pragma unroll
      for (int n = 0; n < 3; ++n)
#pragma unroll
        for (int m = 0; m < 4; ++m)
          acc[n][m] = __builtin_amdgcn_mfma_f32_16x16x32_bf16(cur.a[m], cur.b[n],
                                                              acc[n][m], 0, 0, 0);
      if (kc + 4 < 16) {
        if (sc1a) issue7_sc1(a0, a1, a2, a3, bp, pipe[kc & 3]);
        else      issue7_plain(a0, a1, a2, a3, bp, pipe[kc & 3]);
        a0 += 32; a1 += 32; a2 += 32; a3 += 32; bp += 1536;
      }
    }

    // ---- cross-wave reduction (waves 1-3 -> LDS, wave 0 combines) ----
    if (wv > 0) {
      f32x4* dst = (f32x4*)(red + ((size_t)(wv - 1) * 64 + lane) * 208);
#pragma unroll
      for (int n = 0; n < 3; ++n)
#pragma unroll
        for (int m = 0; m < 4; ++m) dst[n * 4 + m] = acc[n][m];
    }
    __syncthreads();

    if (wv == 0) {
      const f32x4* s1 = (const f32x4*)(red + (size_t)(0 * 64 + lane) * 208);
      const f32x4* s2 = (const f32x4*)(red + (size_t)(1 * 64 + lane) * 208);
      const f32x4* s3 = (const f32x4*)(red + (size_t)(2 * 64 + lane) * 208);
      f32x4 nx[4];
#pragma unroll
      for (int m = 0; m < 4; ++m) {
        acc[0][m] += s1[m] + s2[m] + s3[m];            // r: all waves
        acc[1][m] += s1[4 + m] + s2[4 + m] + s3[4 + m];// z: all waves
        acc[2][m] += s1[8 + m];                        // n h-part (waves 0+1)
        nx[m] = s2[8 + m] + s3[8 + m];                 // n x-part (waves 2+3)
      }
      uint16_t* hdst = hwr + (size_t)(t & 1) * HB;
      uint16_t* odst = o0r + (size_t)(t & 7) * HB;
#pragma unroll
      for (int m = 0; m < 4; ++m) {
#pragma unroll
        for (int rg = 0; rg < 4; ++rg) {
          float rr = sigmoid_fast(acc[0][m][rg] + bR);
          float zz = sigmoid_fast(acc[1][m][rg] + bZ);
          float nn = tanh_fast(nx[m][rg] + bihN + rr * (acc[2][m][rg] + bhhN));
          float h = (1.0f - zz) * nn + zz * hreg[m][rg];
          hreg[m][rg] = h;
          int row = m * 16 + q * 4 + rg;
          uint16_t h16 = f32_to_bf16(h);
          st_u16_llc(hdst + (size_t)row * 1024 + c, h16);
          if (task == 0) st_u16_llc(odst + (size_t)row * 1024 + c, h16);
          else out[(size_t)t * HB + (size_t)row * 1024 + c] = h;
        }
      }
      drain_vmem();                                    // this wave's stores at LLC
      __hip_atomic_store(myF + s, t + 1, __ATOMIC_RELAXED, __HIP_MEMORY_SCOPE_AGENT);
    }
  }

  // final hidden state (L,B,H) appended after the output sequence
  if (wv == 0) {
#pragma unroll
    for (int m = 0; m < 4; ++m)
#pragma unroll
      for (int rg = 0; rg < 4; ++rg)
        out[(size_t)SLEN * HB + (size_t)task * HB +
            (size_t)(m * 16 + q * 4 + rg) * 1024 + c] = hreg[m][rg];
  }
}

// ---- host -------------------------------------------------------------------

extern "C" void kernel_launch(void* const* d_in, const int* in_sizes, int n_in,
                              void* d_out, int out_size, void* d_ws, size_t ws_size,
                              hipStream_t stream) {
  (void)in_sizes; (void)n_in; (void)out_size; (void)ws_size;
  const float* x = (const float*)d_in[0];
  const float* hx = (const float*)d_in[1];
  const float* wih0f = (const float*)d_in[2];
  const float* whh0f = (const float*)d_in[3];
  const float* bih0 = (const float*)d_in[4];
  const float* bhh0 = (const float*)d_in[5];
  const float* wih1f = (const float*)d_in[6];
  const float* whh1f = (const float*)d_in[7];
  const float* bih1 = (const float*)d_in[8];
  const float* bhh1 = (const float*)d_in[9];
  float* out = (float*)d_out;

  char* ws = (char*)d_ws;
  uint16_t* x_bf = (uint16_t*)ws; ws += (size_t)SLEN * HB * 2;       // 64 MB
  uint16_t* w0cat = (uint16_t*)ws; ws += (size_t)64 * 4 * 24576 * 2; // 12.6 MB
  uint16_t* w1cat = (uint16_t*)ws; ws += (size_t)64 * 4 * 24576 * 2; // 12.6 MB
  uint16_t* o0r = (uint16_t*)ws; ws += (size_t)8 * HB * 2;           // 1 MB ring
  uint16_t* h0b = (uint16_t*)ws; ws += (size_t)2 * HB * 2;           // 256 KB
  uint16_t* h1b = (uint16_t*)ws; ws += (size_t)2 * HB * 2;
  int* flags = (int*)ws; ws += 1024;

  convert_x<<<16384, 256, 0, stream>>>(x, x_bf);
  pack_cat<<<3072, 256, 0, stream>>>(whh0f, wih0f, w0cat);
  pack_cat<<<3072, 256, 0, stream>>>(whh1f, wih1f, w1cat);
  init_state<<<256, 256, 0, stream>>>(hx, h0b, h1b, flags);

  const uint16_t* cx = x_bf;
  const uint16_t* cw0 = w0cat;
  const uint16_t* cw1 = w1cat;
  void* args[] = {(void*)&cx, (void*)&cw0, (void*)&cw1,
                  (void*)&bih0, (void*)&bhh0, (void*)&bih1, (void*)&bhh1,
                  (void*)&hx, (void*)&o0r, (void*)&h0b, (void*)&h1b,
                  (void*)&flags, (void*)&out};
  hipError_t e = hipLaunchCooperativeKernel(reinterpret_cast<void*>(gru_persist),
                                            dim3(128), dim3(256), args, 0u, stream);
  if (e != hipSuccess) {
    // 128 WGs at 1 WG/CU are co-resident on 256 CUs in practice
    gru_persist<<<dim3(128), dim3(256), 0, stream>>>(
        x_bf, w0cat, w1cat, bih0, bhh0, bih1, bhh1, hx, o0r, h0b, h1b, flags, out);
  }
}